// Round 1
// baseline (977.705 us; speedup 1.0000x reference)
//
#include <hip/hip_runtime.h>
#include <math.h>

// Problem constants
#define NB_ 3
#define B_ 4
#define N_ 1024
#define CQ_ 128
#define CKV_ 64
#define CP_ 16
#define H_ 4
#define D_ 32
#define R_ (B_*N_)      // 4096 rows
#define KW_ 128         // local key window width

__device__ __forceinline__ float sigmoidf_(float x) {
    return 1.0f / (1.0f + __expf(-x));
}

// ---------------------------------------------------------------------------
// Kernel A: fused LN(a), LN(c), AdaLN gate/skip matmuls (K=64), and the two
// sigmoid(c@ws_out + bs_out) output gates, for attn + transition paths.
// grid = R/16, block = 256.
// ---------------------------------------------------------------------------
__global__ __launch_bounds__(256) void k_adaln(
    const float* __restrict__ a, const float* __restrict__ c,
    const float* __restrict__ a_sg, const float* __restrict__ a_gw,
    const float* __restrict__ a_sw, const float* __restrict__ a_wso,
    const float* __restrict__ a_bso,
    const float* __restrict__ t_sg, const float* __restrict__ t_gw,
    const float* __restrict__ t_sw, const float* __restrict__ t_wso,
    const float* __restrict__ t_bso,
    float* __restrict__ ah, float* __restrict__ th,
    float* __restrict__ asig, float* __restrict__ tsig)
{
    __shared__ float an[16][128];
    __shared__ float sA[16][64];
    __shared__ float sT[16][64];
    __shared__ float cr[16][64];

    const int t = threadIdx.x;
    const int rloc = t >> 4, li = t & 15;
    const int row = blockIdx.x * 16 + rloc;

    // ---- phase 1: per-row LN stats (16 threads per row) ----
    const float* arow = a + row * 128 + li * 8;
    float4 av0 = *(const float4*)(arow);
    float4 av1 = *(const float4*)(arow + 4);
    float s  = av0.x + av0.y + av0.z + av0.w + av1.x + av1.y + av1.z + av1.w;
    float ss = av0.x*av0.x + av0.y*av0.y + av0.z*av0.z + av0.w*av0.w
             + av1.x*av1.x + av1.y*av1.y + av1.z*av1.z + av1.w*av1.w;
    float4 cv = *(const float4*)(c + row * 64 + li * 4);
    float cs  = cv.x + cv.y + cv.z + cv.w;
    float css = cv.x*cv.x + cv.y*cv.y + cv.z*cv.z + cv.w*cv.w;
    #pragma unroll
    for (int m = 1; m < 16; m <<= 1) {
        s   += __shfl_xor(s, m);
        ss  += __shfl_xor(ss, m);
        cs  += __shfl_xor(cs, m);
        css += __shfl_xor(css, m);
    }
    const float am  = s * (1.0f / 128.0f);
    const float ars = rsqrtf(ss * (1.0f / 128.0f) - am * am + 1e-5f);
    const float cm  = cs * (1.0f / 64.0f);
    const float crs = rsqrtf(css * (1.0f / 64.0f) - cm * cm + 1e-5f);

    float avals[8] = {av0.x, av0.y, av0.z, av0.w, av1.x, av1.y, av1.z, av1.w};
    #pragma unroll
    for (int e = 0; e < 8; e++)
        an[rloc][li * 8 + e] = (avals[e] - am) * ars;
    float cvals[4] = {cv.x, cv.y, cv.z, cv.w};
    #pragma unroll
    for (int e = 0; e < 4; e++) {
        const int idx = li * 4 + e;
        const float cn = (cvals[e] - cm) * crs;
        sA[rloc][idx] = cn * a_sg[idx];
        sT[rloc][idx] = cn * t_sg[idx];
        cr[rloc][idx] = cvals[e];
    }
    __syncthreads();

    // ---- phase 2: 6 GEMV-ish dots per output column, 8 rows per thread ----
    const int c2 = t & 127, rh = t >> 7;
    float gA[8], sAc[8], gT[8], sTc[8], oA[8], oT[8];
    const float bsoA = a_bso[c2], bsoT = t_bso[c2];
    #pragma unroll
    for (int j = 0; j < 8; j++) {
        gA[j] = 0.f; sAc[j] = 0.f; gT[j] = 0.f; sTc[j] = 0.f;
        oA[j] = bsoA; oT[j] = bsoT;
    }
    for (int k = 0; k < 64; k++) {
        const float wga = a_gw[k * 128 + c2];
        const float wsa = a_sw[k * 128 + c2];
        const float woa = a_wso[k * 128 + c2];
        const float wgt = t_gw[k * 128 + c2];
        const float wst = t_sw[k * 128 + c2];
        const float wot = t_wso[k * 128 + c2];
        #pragma unroll
        for (int j = 0; j < 8; j++) {
            const int r = rh * 8 + j;
            const float xa = sA[r][k], xt = sT[r][k], xc = cr[r][k];
            gA[j]  += xa * wga;  sAc[j] += xa * wsa;
            gT[j]  += xt * wgt;  sTc[j] += xt * wst;
            oA[j]  += xc * woa;  oT[j]  += xc * wot;
        }
    }
    #pragma unroll
    for (int j = 0; j < 8; j++) {
        const int r = rh * 8 + j;
        const int idx = (blockIdx.x * 16 + r) * 128 + c2;
        const float anv = an[r][c2];
        ah[idx]   = sigmoidf_(gA[j]) * anv + sAc[j];
        th[idx]   = sigmoidf_(gT[j]) * anv + sTc[j];
        asig[idx] = sigmoidf_(oA[j]);
        tsig[idx] = sigmoidf_(oT[j]);
    }
}

// ---------------------------------------------------------------------------
// Kernel B: qh/kh/vh/g = ah @ {wq,wk,wv,wgate} (K=128), +bq on q, sigmoid on g.
// grid = R/16, block = 256.
// ---------------------------------------------------------------------------
__global__ __launch_bounds__(256) void k_qkvg(
    const float* __restrict__ ah,
    const float* __restrict__ wq, const float* __restrict__ bq,
    const float* __restrict__ wk, const float* __restrict__ wv,
    const float* __restrict__ wg,
    float* __restrict__ qh, float* __restrict__ kh,
    float* __restrict__ vh, float* __restrict__ gh)
{
    __shared__ float at[16][128];
    const int t = threadIdx.x;
    const int base = blockIdx.x * 16;
    #pragma unroll
    for (int i = 0; i < 8; i++) {
        const int e = t + i * 256;
        at[e >> 7][e & 127] = ah[(base + (e >> 7)) * 128 + (e & 127)];
    }
    __syncthreads();
    const int c2 = t & 127, rh = t >> 7;
    float aq[8], ak[8], av[8], ag[8];
    const float bqv = bq[c2];
    #pragma unroll
    for (int j = 0; j < 8; j++) { aq[j] = bqv; ak[j] = 0.f; av[j] = 0.f; ag[j] = 0.f; }
    for (int kd = 0; kd < 128; kd++) {
        const float wqv = wq[kd * 128 + c2];
        const float wkv = wk[kd * 128 + c2];
        const float wvv = wv[kd * 128 + c2];
        const float wgv = wg[kd * 128 + c2];
        #pragma unroll
        for (int j = 0; j < 8; j++) {
            const float x = at[rh * 8 + j][kd];
            aq[j] += x * wqv; ak[j] += x * wkv;
            av[j] += x * wvv; ag[j] += x * wgv;
        }
    }
    #pragma unroll
    for (int j = 0; j < 8; j++) {
        const int idx = (base + rh * 8 + j) * 128 + c2;
        qh[idx] = aq[j]; kh[idx] = ak[j]; vh[idx] = av[j];
        gh[idx] = sigmoidf_(ag[j]);
    }
}

// ---------------------------------------------------------------------------
// Kernel Z: z-bias for ALL 3 blocks in one pass over the local p window.
// One thread per (b, n, kk) pair. zb layout: [NB][R][H][KW].
// Invalid (out-of-range) keys get -1e10 (== beta mask; kills softmax weight).
// grid = B*N*KW/256 = 2048, block = 256.
// ---------------------------------------------------------------------------
__global__ __launch_bounds__(256) void k_zbias(
    const float* __restrict__ p,
    const float* __restrict__ lnz_g, const float* __restrict__ lnz_b,
    const float* __restrict__ wb, float* __restrict__ zb)
{
    const int tid = blockIdx.x * 256 + threadIdx.x;
    const int kk = tid & 127;
    const int n = (tid >> 7) & 1023;
    const int b = tid >> 17;
    const int row = b * N_ + n;
    const int k = ((n >> 5) << 5) - 48 + kk;

    if (k < 0 || k >= N_) {
        #pragma unroll
        for (int blk = 0; blk < NB_; blk++) {
            float* zo = zb + ((size_t)(blk * R_ + row) * H_) * KW_ + kk;
            #pragma unroll
            for (int h = 0; h < H_; h++) zo[h * KW_] = -1e10f;
        }
        return;
    }
    const float* pp = p + ((size_t)row * N_ + k) * CP_;
    float pv[16];
    float4 p0 = *(const float4*)(pp);
    float4 p1 = *(const float4*)(pp + 4);
    float4 p2 = *(const float4*)(pp + 8);
    float4 p3 = *(const float4*)(pp + 12);
    pv[0]=p0.x; pv[1]=p0.y; pv[2]=p0.z; pv[3]=p0.w;
    pv[4]=p1.x; pv[5]=p1.y; pv[6]=p1.z; pv[7]=p1.w;
    pv[8]=p2.x; pv[9]=p2.y; pv[10]=p2.z; pv[11]=p2.w;
    pv[12]=p3.x; pv[13]=p3.y; pv[14]=p3.z; pv[15]=p3.w;
    float s = 0.f, ss = 0.f;
    #pragma unroll
    for (int i = 0; i < 16; i++) { s += pv[i]; ss += pv[i] * pv[i]; }
    const float m = s * (1.0f / 16.0f);
    const float rs = rsqrtf(ss * (1.0f / 16.0f) - m * m + 1e-5f);

    #pragma unroll
    for (int blk = 0; blk < NB_; blk++) {
        const float* g = lnz_g + blk * 16;
        const float* bb = lnz_b + blk * 16;
        const float* w = wb + blk * 64;
        float z0 = 0.f, z1 = 0.f, z2 = 0.f, z3 = 0.f;
        #pragma unroll
        for (int cp = 0; cp < 16; cp++) {
            const float val = (pv[cp] - m) * rs * g[cp] + bb[cp];
            z0 += val * w[cp * 4 + 0];
            z1 += val * w[cp * 4 + 1];
            z2 += val * w[cp * 4 + 2];
            z3 += val * w[cp * 4 + 3];
        }
        float* zo = zb + ((size_t)(blk * R_ + row) * H_) * KW_ + kk;
        zo[0] = z0; zo[KW_] = z1; zo[2 * KW_] = z2; zo[3 * KW_] = z3;
    }
}

// ---------------------------------------------------------------------------
// Kernel C: local attention. grid = (32 qblocks, H, B), block = 256.
// 32 queries x 128-key window per workgroup; bias from zb; output og = g * o.
// ---------------------------------------------------------------------------
__global__ __launch_bounds__(256) void k_attn(
    const float* __restrict__ qh, const float* __restrict__ kh,
    const float* __restrict__ vh, const float* __restrict__ gh,
    const float* __restrict__ zb, float* __restrict__ og)
{
    __shared__ float kT[32][136];   // [d][kk], padded: conflict-free + 16B aligned
    __shared__ float vs[128][36];   // [kk][d]
    __shared__ float wsm[32][132];  // softmax weights [q][kk]

    const int t = threadIdx.x;
    const int qb = blockIdx.x, h = blockIdx.y, b = blockIdx.z;
    const int k0 = qb * 32 - 48;

    #pragma unroll
    for (int i = 0; i < 16; i++) {
        const int e = t + i * 256;
        const int kk = e >> 5, d = e & 31;
        const int kg = k0 + kk;
        float kvv = 0.f, vvv = 0.f;
        if (kg >= 0 && kg < N_) {
            const int addr = (b * N_ + kg) * 128 + h * 32 + d;
            kvv = kh[addr]; vvv = vh[addr];
        }
        kT[d][kk] = kvv;
        vs[kk][d] = vvv;
    }

    const int q = t >> 3, j = t & 7;
    const int n = qb * 32 + q;
    const float* qrow = qh + (b * N_ + n) * 128 + h * 32;
    float4 qf[8];
    #pragma unroll
    for (int dq = 0; dq < 8; dq++) qf[dq] = *(const float4*)(qrow + dq * 4);
    const float* zrow = zb + ((size_t)(b * N_ + n) * H_ + h) * KW_;
    float4 zf[4];
    #pragma unroll
    for (int g4 = 0; g4 < 4; g4++) zf[g4] = *(const float4*)(zrow + j * 16 + g4 * 4);
    __syncthreads();

    float4 acc[4];
    #pragma unroll
    for (int g4 = 0; g4 < 4; g4++) acc[g4] = make_float4(0.f, 0.f, 0.f, 0.f);
    const float* qfs = (const float*)qf;
    for (int d = 0; d < 32; d++) {
        const float qd = qfs[d];
        #pragma unroll
        for (int g4 = 0; g4 < 4; g4++) {
            const float4 k4 = *(const float4*)&kT[d][j * 16 + g4 * 4];
            acc[g4].x += qd * k4.x; acc[g4].y += qd * k4.y;
            acc[g4].z += qd * k4.z; acc[g4].w += qd * k4.w;
        }
    }
    const float scale = 0.1767766952966369f;  // 1/sqrt(32)
    float fr[16];
    #pragma unroll
    for (int g4 = 0; g4 < 4; g4++) {
        fr[g4*4+0] = zf[g4].x + acc[g4].x * scale;
        fr[g4*4+1] = zf[g4].y + acc[g4].y * scale;
        fr[g4*4+2] = zf[g4].z + acc[g4].z * scale;
        fr[g4*4+3] = zf[g4].w + acc[g4].w * scale;
    }
    float mx = fr[0];
    #pragma unroll
    for (int i = 1; i < 16; i++) mx = fmaxf(mx, fr[i]);
    #pragma unroll
    for (int mk = 1; mk < 8; mk <<= 1) mx = fmaxf(mx, __shfl_xor(mx, mk));
    float sum = 0.f;
    #pragma unroll
    for (int i = 0; i < 16; i++) { fr[i] = __expf(fr[i] - mx); sum += fr[i]; }
    #pragma unroll
    for (int mk = 1; mk < 8; mk <<= 1) sum += __shfl_xor(sum, mk);
    const float rinv = 1.0f / sum;
    #pragma unroll
    for (int g4 = 0; g4 < 4; g4++)
        #pragma unroll
        for (int mm = 0; mm < 4; mm++)
            wsm[q][j * 16 + g4 * 4 + mm] = fr[g4 * 4 + mm] * rinv;
    __syncthreads();

    // O = W @ V ; 4 output dims per thread
    const int q2 = t >> 3, dg = t & 7;
    float4 o = make_float4(0.f, 0.f, 0.f, 0.f);
    for (int kk = 0; kk < 128; kk++) {
        const float wv_ = wsm[q2][kk];
        const float4 v4 = *(const float4*)&vs[kk][dg * 4];
        o.x += wv_ * v4.x; o.y += wv_ * v4.y;
        o.z += wv_ * v4.z; o.w += wv_ * v4.w;
    }
    const int n2 = qb * 32 + q2;
    const int addr = (b * N_ + n2) * 128 + h * 32 + dg * 4;
    const float4 g4v = *(const float4*)(gh + addr);
    float4 outv;
    outv.x = o.x * g4v.x; outv.y = o.y * g4v.y;
    outv.z = o.z * g4v.z; outv.w = o.w * g4v.w;
    *(float4*)(og + addr) = outv;
}

// ---------------------------------------------------------------------------
// Kernel D1: bm = silu(th@w1) * (th@w2).  grid = R/8, block = 256.
// ---------------------------------------------------------------------------
__global__ __launch_bounds__(256) void k_bm(
    const float* __restrict__ th, const float* __restrict__ w1,
    const float* __restrict__ w2, float* __restrict__ bm)
{
    __shared__ float tl[8][128];
    const int t = threadIdx.x;
    const int base = blockIdx.x * 8;
    #pragma unroll
    for (int i = 0; i < 4; i++) {
        const int e = t + i * 256;
        tl[e >> 7][e & 127] = th[(base + (e >> 7)) * 128 + (e & 127)];
    }
    __syncthreads();
    float a1[8], a2[8];
    #pragma unroll
    for (int r = 0; r < 8; r++) { a1[r] = 0.f; a2[r] = 0.f; }
    for (int kd = 0; kd < 128; kd++) {
        const float w1v = w1[kd * 256 + t];
        const float w2v = w2[kd * 256 + t];
        #pragma unroll
        for (int r = 0; r < 8; r++) {
            const float x = tl[r][kd];
            a1[r] += x * w1v; a2[r] += x * w2v;
        }
    }
    #pragma unroll
    for (int r = 0; r < 8; r++) {
        const float x1 = a1[r];
        bm[(base + r) * 256 + t] = x1 * sigmoidf_(x1) * a2[r];
    }
}

// ---------------------------------------------------------------------------
// Kernel D2: out = asig * (og@wo) + tsig * (bm@wout).  grid = R/16, block 256.
// ---------------------------------------------------------------------------
__global__ __launch_bounds__(256) void k_combine(
    const float* __restrict__ og, const float* __restrict__ bm,
    const float* __restrict__ wo, const float* __restrict__ wout,
    const float* __restrict__ asig, const float* __restrict__ tsig,
    float* __restrict__ out)
{
    __shared__ float ol[16][128];
    __shared__ float bl[16][256];
    const int t = threadIdx.x;
    const int base = blockIdx.x * 16;
    #pragma unroll
    for (int i = 0; i < 8; i++) {
        const int e = t + i * 256;
        ol[e >> 7][e & 127] = og[(base + (e >> 7)) * 128 + (e & 127)];
    }
    #pragma unroll
    for (int i = 0; i < 16; i++) {
        const int e = t + i * 256;
        bl[e >> 8][e & 255] = bm[(base + (e >> 8)) * 256 + (e & 255)];
    }
    __syncthreads();
    const int c2 = t & 127, rh = t >> 7;
    float acc1[8], acc2[8];
    #pragma unroll
    for (int j = 0; j < 8; j++) { acc1[j] = 0.f; acc2[j] = 0.f; }
    for (int kd = 0; kd < 128; kd++) {
        const float wv = wo[kd * 128 + c2];
        #pragma unroll
        for (int j = 0; j < 8; j++) acc1[j] += ol[rh * 8 + j][kd] * wv;
    }
    for (int kd = 0; kd < 256; kd++) {
        const float wv = wout[kd * 128 + c2];
        #pragma unroll
        for (int j = 0; j < 8; j++) acc2[j] += bl[rh * 8 + j][kd] * wv;
    }
    #pragma unroll
    for (int j = 0; j < 8; j++) {
        const int idx = (base + rh * 8 + j) * 128 + c2;
        out[idx] = asig[idx] * acc1[j] + tsig[idx] * acc2[j];
    }
}

// ---------------------------------------------------------------------------
extern "C" void kernel_launch(void* const* d_in, const int* in_sizes, int n_in,
                              void* d_out, int out_size, void* d_ws, size_t ws_size,
                              hipStream_t stream)
{
    const float* q        = (const float*)d_in[0];
    const float* c        = (const float*)d_in[1];
    const float* p        = (const float*)d_in[2];
    const float* a_sg_all = (const float*)d_in[3];
    const float* a_gw_all = (const float*)d_in[4];
    const float* a_sw_all = (const float*)d_in[5];
    const float* wq_all   = (const float*)d_in[6];
    const float* bq_all   = (const float*)d_in[7];
    const float* wk_all   = (const float*)d_in[8];
    const float* wv_all   = (const float*)d_in[9];
    const float* lnzg_all = (const float*)d_in[10];
    const float* lnzb_all = (const float*)d_in[11];
    const float* wb_all   = (const float*)d_in[12];
    const float* wgt_all  = (const float*)d_in[13];
    const float* wo_all   = (const float*)d_in[14];
    const float* awso_all = (const float*)d_in[15];
    const float* abso_all = (const float*)d_in[16];
    const float* t_sg_all = (const float*)d_in[17];
    const float* t_gw_all = (const float*)d_in[18];
    const float* t_sw_all = (const float*)d_in[19];
    const float* w1_all   = (const float*)d_in[20];
    const float* w2_all   = (const float*)d_in[21];
    const float* wout_all = (const float*)d_in[22];
    const float* twso_all = (const float*)d_in[23];
    const float* tbso_all = (const float*)d_in[24];

    float* ws = (float*)d_ws;
    const size_t RC = (size_t)R_ * CQ_;   // 524288
    float* a_buf = ws;
    float* ah    = ws + RC;
    float* th    = ws + 2 * RC;
    float* asig  = ws + 3 * RC;
    float* tsig  = ws + 4 * RC;
    float* qh    = ws + 5 * RC;
    float* kh    = ws + 6 * RC;
    float* vh    = ws + 7 * RC;
    float* gh    = ws + 8 * RC;
    float* ogb   = ws + 9 * RC;
    float* bmb   = ws + 10 * RC;          // R*256 = 2*RC
    float* zbb   = ws + 12 * RC;          // NB*R*H*KW = 12*RC

    // z-bias for all 3 blocks in one pass over the 128-wide key window of p
    k_zbias<<<dim3(B_ * N_ * KW_ / 256), dim3(256), 0, stream>>>(
        p, lnzg_all, lnzb_all, wb_all, zbb);

    const float* acur = q;
    for (int blk = 0; blk < NB_; blk++) {
        k_adaln<<<dim3(R_ / 16), dim3(256), 0, stream>>>(
            acur, c,
            a_sg_all + blk * CKV_, a_gw_all + blk * CKV_ * CQ_,
            a_sw_all + blk * CKV_ * CQ_, awso_all + blk * CKV_ * CQ_,
            abso_all + blk * CQ_,
            t_sg_all + blk * CKV_, t_gw_all + blk * CKV_ * CQ_,
            t_sw_all + blk * CKV_ * CQ_, twso_all + blk * CKV_ * CQ_,
            tbso_all + blk * CQ_,
            ah, th, asig, tsig);
        k_qkvg<<<dim3(R_ / 16), dim3(256), 0, stream>>>(
            ah, wq_all + blk * CQ_ * CQ_, bq_all + blk * CQ_,
            wk_all + blk * CQ_ * CQ_, wv_all + blk * CQ_ * CQ_,
            wgt_all + blk * CQ_ * CQ_, qh, kh, vh, gh);
        k_bm<<<dim3(R_ / 8), dim3(256), 0, stream>>>(
            th, w1_all + blk * CQ_ * 2 * CQ_, w2_all + blk * CQ_ * 2 * CQ_, bmb);
        k_attn<<<dim3(N_ / 32, H_, B_), dim3(256), 0, stream>>>(
            qh, kh, vh, gh, zbb + (size_t)blk * R_ * H_ * KW_, ogb);
        float* outp = (blk == NB_ - 1) ? (float*)d_out : a_buf;
        k_combine<<<dim3(R_ / 16), dim3(256), 0, stream>>>(
            ogb, bmb, wo_all + blk * CQ_ * CQ_, wout_all + blk * 2 * CQ_ * CQ_,
            asig, tsig, outp);
        acur = a_buf;
    }
}

// Round 2
// 648.533 us; speedup vs baseline: 1.5076x; 1.5076x over previous
//
#include <hip/hip_runtime.h>
#include <math.h>

#define NB_ 3
#define B_ 4
#define N_ 1024
#define CQ_ 128
#define CKV_ 64
#define CP_ 16
#define H_ 4
#define D_ 32
#define R_ (B_*N_)
#define KW_ 128

__device__ __forceinline__ float sigmoidf_(float x) {
    return 1.0f / (1.0f + __expf(-x));
}

// ---------------------------------------------------------------------------
// k_pre: fused AdaLN (attn+trans) + qkvg projections + transition silu-mul.
// grid = R/8 = 512 blocks, 512 threads (8 waves). 8 rows per block.
// LDS layout (floats, manual offsets; rows padded to break bank aliasing):
//   AN/AH 8x132, SA/ST/CR 8x68, TH 8x132, SCR 6x8x132 (aliased bmacc 2x8x260)
// ---------------------------------------------------------------------------
#define AN_OFF 0
#define SA_OFF 1056
#define ST_OFF 1600
#define CR_OFF 2144
#define TH_OFF 2688
#define SCR_OFF 3744
#define SMEM_F (3744 + 6336)

__global__ __launch_bounds__(512, 4) void k_pre(
    const float* __restrict__ a, const float* __restrict__ c,
    const float* __restrict__ a_sg, const float* __restrict__ a_gw,
    const float* __restrict__ a_sw, const float* __restrict__ a_wso,
    const float* __restrict__ a_bso,
    const float* __restrict__ t_sg, const float* __restrict__ t_gw,
    const float* __restrict__ t_sw, const float* __restrict__ t_wso,
    const float* __restrict__ t_bso,
    const float* __restrict__ wq, const float* __restrict__ bq,
    const float* __restrict__ wk, const float* __restrict__ wv,
    const float* __restrict__ wg,
    const float* __restrict__ w1, const float* __restrict__ w2,
    float* __restrict__ qh, float* __restrict__ kh,
    float* __restrict__ vh, float* __restrict__ gh,
    float* __restrict__ bm,
    float* __restrict__ asig, float* __restrict__ tsig)
{
    __shared__ float smem[SMEM_F];
    const int t = threadIdx.x;
    const int base = blockIdx.x * 8;

    // ---- phase 1: LN stats, one wave per row ----
    {
        const int rloc = t >> 6, li = t & 63;
        const int row = base + rloc;
        float2 av = *(const float2*)(a + row * 128 + li * 2);
        float s = av.x + av.y;
        float ss = av.x * av.x + av.y * av.y;
        float cv = c[row * 64 + li];
        float cs = cv, css = cv * cv;
        #pragma unroll
        for (int m = 1; m < 64; m <<= 1) {
            s += __shfl_xor(s, m);
            ss += __shfl_xor(ss, m);
            cs += __shfl_xor(cs, m);
            css += __shfl_xor(css, m);
        }
        const float am = s * (1.0f / 128.0f);
        const float ars = rsqrtf(ss * (1.0f / 128.0f) - am * am + 1e-5f);
        const float cm = cs * (1.0f / 64.0f);
        const float crs = rsqrtf(css * (1.0f / 64.0f) - cm * cm + 1e-5f);
        smem[AN_OFF + rloc * 132 + li * 2]     = (av.x - am) * ars;
        smem[AN_OFF + rloc * 132 + li * 2 + 1] = (av.y - am) * ars;
        const float cn = (cv - cm) * crs;
        smem[SA_OFF + rloc * 68 + li] = cn * a_sg[li];
        smem[ST_OFF + rloc * 68 + li] = cn * t_sg[li];
        smem[CR_OFF + rloc * 68 + li] = cv;
    }
    __syncthreads();

    const int wave = t >> 6;
    const int lane = t & 63;
    const int ig = lane >> 4;       // row pair group 0..3
    const int jc = lane & 15;       // col group
    const int c0 = jc * 8;
    const int r0 = ig * 2, r1 = ig * 2 + 1;

    // ---- phase 2: six K=64 GEMVs, one matrix per wave (waves 0..5) ----
    if (wave < 6) {
        const float* W;
        const float* xs;
        switch (wave) {
            case 0: W = a_gw;  xs = smem + SA_OFF; break;
            case 1: W = a_sw;  xs = smem + SA_OFF; break;
            case 2: W = t_gw;  xs = smem + ST_OFF; break;
            case 3: W = t_sw;  xs = smem + ST_OFF; break;
            case 4: W = a_wso; xs = smem + CR_OFF; break;
            default: W = t_wso; xs = smem + CR_OFF; break;
        }
        W += c0;
        float acc0[8], acc1[8];
        #pragma unroll
        for (int e = 0; e < 8; e++) { acc0[e] = 0.f; acc1[e] = 0.f; }
        for (int kk = 0; kk < 64; kk += 4) {
            float4 x40 = *(const float4*)(xs + r0 * 68 + kk);
            float4 x41 = *(const float4*)(xs + r1 * 68 + kk);
            #pragma unroll
            for (int q = 0; q < 4; q++) {
                const float4 wlo = *(const float4*)(W + (kk + q) * 128);
                const float4 whi = *(const float4*)(W + (kk + q) * 128 + 4);
                const float xa = ((const float*)&x40)[q];
                const float xb = ((const float*)&x41)[q];
                acc0[0] += xa * wlo.x; acc0[1] += xa * wlo.y;
                acc0[2] += xa * wlo.z; acc0[3] += xa * wlo.w;
                acc0[4] += xa * whi.x; acc0[5] += xa * whi.y;
                acc0[6] += xa * whi.z; acc0[7] += xa * whi.w;
                acc1[0] += xb * wlo.x; acc1[1] += xb * wlo.y;
                acc1[2] += xb * wlo.z; acc1[3] += xb * wlo.w;
                acc1[4] += xb * whi.x; acc1[5] += xb * whi.y;
                acc1[6] += xb * whi.z; acc1[7] += xb * whi.w;
            }
        }
        float* sc = smem + SCR_OFF + wave * 1056;
        *(float4*)(sc + r0 * 132 + c0)     = make_float4(acc0[0], acc0[1], acc0[2], acc0[3]);
        *(float4*)(sc + r0 * 132 + c0 + 4) = make_float4(acc0[4], acc0[5], acc0[6], acc0[7]);
        *(float4*)(sc + r1 * 132 + c0)     = make_float4(acc1[0], acc1[1], acc1[2], acc1[3]);
        *(float4*)(sc + r1 * 132 + c0 + 4) = make_float4(acc1[4], acc1[5], acc1[6], acc1[7]);
    }
    __syncthreads();

    // ---- phase 3: combine -> ah (in-place over AN), th, asig/tsig ----
    #pragma unroll
    for (int i2 = 0; i2 < 2; i2++) {
        const int e = t + i2 * 512;       // 1024 entries: 8 rows x 128 cols
        const int r = e >> 7, cc = e & 127;
        const float* sc = smem + SCR_OFF + r * 132 + cc;
        const float anv = smem[AN_OFF + r * 132 + cc];
        const float ahv = sigmoidf_(sc[0]) * anv + sc[1056];
        const float thv = sigmoidf_(sc[2 * 1056]) * anv + sc[3 * 1056];
        smem[AN_OFF + r * 132 + cc] = ahv;
        smem[TH_OFF + r * 132 + cc] = thv;
        const int idx = (base + r) * 128 + cc;
        asig[idx] = sigmoidf_(sc[4 * 1056] + a_bso[cc]);
        tsig[idx] = sigmoidf_(sc[5 * 1056] + t_bso[cc]);
    }
    __syncthreads();

    // ---- phase 4: K=128 GEMMs. waves 0-3: qkvg from AH; 4-7: w1/w2 from TH ----
    {
        const float* W;
        const float* xs;
        int ldw, sel2 = 0, cb = 0;
        if (wave < 4) {
            W = (wave == 0 ? wq : wave == 1 ? wk : wave == 2 ? wv : wg) + c0;
            xs = smem + AN_OFF;
            ldw = 128;
        } else {
            const int u = (wave - 4) * 128 + c0;
            sel2 = u >> 8; cb = u & 255;
            W = (sel2 ? w2 : w1) + cb;
            xs = smem + TH_OFF;
            ldw = 256;
        }
        float acc0[8], acc1[8];
        #pragma unroll
        for (int e = 0; e < 8; e++) {
            const float init = (wave == 0) ? bq[c0 + e] : 0.f;
            acc0[e] = init; acc1[e] = init;
        }
        for (int kk = 0; kk < 128; kk += 4) {
            float4 x40 = *(const float4*)(xs + r0 * 132 + kk);
            float4 x41 = *(const float4*)(xs + r1 * 132 + kk);
            #pragma unroll
            for (int q = 0; q < 4; q++) {
                const float4 wlo = *(const float4*)(W + (kk + q) * ldw);
                const float4 whi = *(const float4*)(W + (kk + q) * ldw + 4);
                const float xa = ((const float*)&x40)[q];
                const float xb = ((const float*)&x41)[q];
                acc0[0] += xa * wlo.x; acc0[1] += xa * wlo.y;
                acc0[2] += xa * wlo.z; acc0[3] += xa * wlo.w;
                acc0[4] += xa * whi.x; acc0[5] += xa * whi.y;
                acc0[6] += xa * whi.z; acc0[7] += xa * whi.w;
                acc1[0] += xb * wlo.x; acc1[1] += xb * wlo.y;
                acc1[2] += xb * wlo.z; acc1[3] += xb * wlo.w;
                acc1[4] += xb * whi.x; acc1[5] += xb * whi.y;
                acc1[6] += xb * whi.z; acc1[7] += xb * whi.w;
            }
        }
        if (wave < 4) {
            float* dst = (wave == 0 ? qh : wave == 1 ? kh : wave == 2 ? vh : gh);
            if (wave == 3) {
                #pragma unroll
                for (int e = 0; e < 8; e++) {
                    acc0[e] = sigmoidf_(acc0[e]);
                    acc1[e] = sigmoidf_(acc1[e]);
                }
            }
            *(float4*)(dst + (base + r0) * 128 + c0)     = make_float4(acc0[0], acc0[1], acc0[2], acc0[3]);
            *(float4*)(dst + (base + r0) * 128 + c0 + 4) = make_float4(acc0[4], acc0[5], acc0[6], acc0[7]);
            *(float4*)(dst + (base + r1) * 128 + c0)     = make_float4(acc1[0], acc1[1], acc1[2], acc1[3]);
            *(float4*)(dst + (base + r1) * 128 + c0 + 4) = make_float4(acc1[4], acc1[5], acc1[6], acc1[7]);
        } else {
            float* bsc = smem + SCR_OFF + sel2 * 2080;
            *(float4*)(bsc + r0 * 260 + cb)     = make_float4(acc0[0], acc0[1], acc0[2], acc0[3]);
            *(float4*)(bsc + r0 * 260 + cb + 4) = make_float4(acc0[4], acc0[5], acc0[6], acc0[7]);
            *(float4*)(bsc + r1 * 260 + cb)     = make_float4(acc1[0], acc1[1], acc1[2], acc1[3]);
            *(float4*)(bsc + r1 * 260 + cb + 4) = make_float4(acc1[4], acc1[5], acc1[6], acc1[7]);
        }
    }
    __syncthreads();

    // ---- phase 4c: bm = silu(a1) * a2 ----
    #pragma unroll
    for (int i2 = 0; i2 < 4; i2++) {
        const int e = t + i2 * 512;       // 2048 = 8 rows x 256 cols
        const int r = e >> 8, cc = e & 255;
        const float a1 = smem[SCR_OFF + r * 260 + cc];
        const float a2 = smem[SCR_OFF + 2080 + r * 260 + cc];
        bm[(base + r) * 256 + cc] = a1 * sigmoidf_(a1) * a2;
    }
}

// ---------------------------------------------------------------------------
// k_zbias: z-bias for all 3 blocks in one pass. zb layout [NB][R][H][KW].
// ---------------------------------------------------------------------------
__global__ __launch_bounds__(256) void k_zbias(
    const float* __restrict__ p,
    const float* __restrict__ lnz_g, const float* __restrict__ lnz_b,
    const float* __restrict__ wb, float* __restrict__ zb)
{
    const int tid = blockIdx.x * 256 + threadIdx.x;
    const int kk = tid & 127;
    const int n = (tid >> 7) & 1023;
    const int b = tid >> 17;
    const int row = b * N_ + n;
    const int k = ((n >> 5) << 5) - 48 + kk;

    if (k < 0 || k >= N_) {
        #pragma unroll
        for (int blk = 0; blk < NB_; blk++) {
            float* zo = zb + ((size_t)(blk * R_ + row) * H_) * KW_ + kk;
            #pragma unroll
            for (int h = 0; h < H_; h++) zo[h * KW_] = -1e10f;
        }
        return;
    }
    const float* pp = p + ((size_t)row * N_ + k) * CP_;
    float pv[16];
    float4 p0 = *(const float4*)(pp);
    float4 p1 = *(const float4*)(pp + 4);
    float4 p2 = *(const float4*)(pp + 8);
    float4 p3 = *(const float4*)(pp + 12);
    pv[0]=p0.x; pv[1]=p0.y; pv[2]=p0.z; pv[3]=p0.w;
    pv[4]=p1.x; pv[5]=p1.y; pv[6]=p1.z; pv[7]=p1.w;
    pv[8]=p2.x; pv[9]=p2.y; pv[10]=p2.z; pv[11]=p2.w;
    pv[12]=p3.x; pv[13]=p3.y; pv[14]=p3.z; pv[15]=p3.w;
    float s = 0.f, ss = 0.f;
    #pragma unroll
    for (int i = 0; i < 16; i++) { s += pv[i]; ss += pv[i] * pv[i]; }
    const float m = s * (1.0f / 16.0f);
    const float rs = rsqrtf(ss * (1.0f / 16.0f) - m * m + 1e-5f);

    #pragma unroll
    for (int blk = 0; blk < NB_; blk++) {
        const float* g = lnz_g + blk * 16;
        const float* bb = lnz_b + blk * 16;
        const float* w = wb + blk * 64;
        float z0 = 0.f, z1 = 0.f, z2 = 0.f, z3 = 0.f;
        #pragma unroll
        for (int cp = 0; cp < 16; cp++) {
            const float val = (pv[cp] - m) * rs * g[cp] + bb[cp];
            z0 += val * w[cp * 4 + 0];
            z1 += val * w[cp * 4 + 1];
            z2 += val * w[cp * 4 + 2];
            z3 += val * w[cp * 4 + 3];
        }
        float* zo = zb + ((size_t)(blk * R_ + row) * H_) * KW_ + kk;
        zo[0] = z0; zo[KW_] = z1; zo[2 * KW_] = z2; zo[3 * KW_] = z3;
    }
}

// ---------------------------------------------------------------------------
// k_attn: local attention, 32 queries x 128-key window per block.
// grid = (32, H, B), block = 256.
// ---------------------------------------------------------------------------
__global__ __launch_bounds__(256) void k_attn(
    const float* __restrict__ qh, const float* __restrict__ kh,
    const float* __restrict__ vh, const float* __restrict__ gh,
    const float* __restrict__ zb, float* __restrict__ og)
{
    __shared__ float kT[32][136];
    __shared__ float vs[128][36];
    __shared__ float wsm[32][132];

    const int t = threadIdx.x;
    const int qb = blockIdx.x, h = blockIdx.y, b = blockIdx.z;
    const int k0 = qb * 32 - 48;

    #pragma unroll
    for (int i = 0; i < 16; i++) {
        const int e = t + i * 256;
        const int kk = e >> 5, d = e & 31;
        const int kg = k0 + kk;
        float kvv = 0.f, vvv = 0.f;
        if (kg >= 0 && kg < N_) {
            const int addr = (b * N_ + kg) * 128 + h * 32 + d;
            kvv = kh[addr]; vvv = vh[addr];
        }
        kT[d][kk] = kvv;
        vs[kk][d] = vvv;
    }

    const int q = t >> 3, j = t & 7;
    const int n = qb * 32 + q;
    const float* qrow = qh + (b * N_ + n) * 128 + h * 32;
    float4 qf[8];
    #pragma unroll
    for (int dq = 0; dq < 8; dq++) qf[dq] = *(const float4*)(qrow + dq * 4);
    const float* zrow = zb + ((size_t)(b * N_ + n) * H_ + h) * KW_;
    float4 zf[4];
    #pragma unroll
    for (int g4 = 0; g4 < 4; g4++) zf[g4] = *(const float4*)(zrow + j * 16 + g4 * 4);
    __syncthreads();

    float4 acc[4];
    #pragma unroll
    for (int g4 = 0; g4 < 4; g4++) acc[g4] = make_float4(0.f, 0.f, 0.f, 0.f);
    const float* qfs = (const float*)qf;
    for (int d = 0; d < 32; d++) {
        const float qd = qfs[d];
        #pragma unroll
        for (int g4 = 0; g4 < 4; g4++) {
            const float4 k4 = *(const float4*)&kT[d][j * 16 + g4 * 4];
            acc[g4].x += qd * k4.x; acc[g4].y += qd * k4.y;
            acc[g4].z += qd * k4.z; acc[g4].w += qd * k4.w;
        }
    }
    const float scale = 0.1767766952966369f;
    float fr[16];
    #pragma unroll
    for (int g4 = 0; g4 < 4; g4++) {
        fr[g4*4+0] = zf[g4].x + acc[g4].x * scale;
        fr[g4*4+1] = zf[g4].y + acc[g4].y * scale;
        fr[g4*4+2] = zf[g4].z + acc[g4].z * scale;
        fr[g4*4+3] = zf[g4].w + acc[g4].w * scale;
    }
    float mx = fr[0];
    #pragma unroll
    for (int i = 1; i < 16; i++) mx = fmaxf(mx, fr[i]);
    #pragma unroll
    for (int mk = 1; mk < 8; mk <<= 1) mx = fmaxf(mx, __shfl_xor(mx, mk));
    float sum = 0.f;
    #pragma unroll
    for (int i = 0; i < 16; i++) { fr[i] = __expf(fr[i] - mx); sum += fr[i]; }
    #pragma unroll
    for (int mk = 1; mk < 8; mk <<= 1) sum += __shfl_xor(sum, mk);
    const float rinv = 1.0f / sum;
    #pragma unroll
    for (int g4 = 0; g4 < 4; g4++)
        #pragma unroll
        for (int mm = 0; mm < 4; mm++)
            wsm[q][j * 16 + g4 * 4 + mm] = fr[g4 * 4 + mm] * rinv;
    __syncthreads();

    const int q2 = t >> 3, dg = t & 7;
    float4 o = make_float4(0.f, 0.f, 0.f, 0.f);
    for (int kk = 0; kk < 128; kk++) {
        const float wv_ = wsm[q2][kk];
        const float4 v4 = *(const float4*)&vs[kk][dg * 4];
        o.x += wv_ * v4.x; o.y += wv_ * v4.y;
        o.z += wv_ * v4.z; o.w += wv_ * v4.w;
    }
    const int n2 = qb * 32 + q2;
    const int addr = (b * N_ + n2) * 128 + h * 32 + dg * 4;
    const float4 g4v = *(const float4*)(gh + addr);
    float4 outv;
    outv.x = o.x * g4v.x; outv.y = o.y * g4v.y;
    outv.z = o.z * g4v.z; outv.w = o.w * g4v.w;
    *(float4*)(og + addr) = outv;
}

// ---------------------------------------------------------------------------
// k_combine: out = asig*(og@wo) + tsig*(bm@wout).
// grid = R/8 = 512, block = 256 (4 waves, K-split: w0/w1 halve wo-K, w2/w3
// halve wout-K), partials exchanged via LDS.
// ---------------------------------------------------------------------------
__global__ __launch_bounds__(256, 4) void k_combine(
    const float* __restrict__ og, const float* __restrict__ bm,
    const float* __restrict__ wo, const float* __restrict__ wout,
    const float* __restrict__ asig, const float* __restrict__ tsig,
    float* __restrict__ out)
{
    __shared__ float scr[4 * 1056];
    const int t = threadIdx.x;
    const int base = blockIdx.x * 8;
    const int wave = t >> 6, lane = t & 63;
    const int ig = lane >> 4, jc = lane & 15;
    const int c0 = jc * 8;
    const int r0 = ig * 2, r1 = ig * 2 + 1;

    float acc0[8], acc1[8];
    #pragma unroll
    for (int e = 0; e < 8; e++) { acc0[e] = 0.f; acc1[e] = 0.f; }

    if (wave < 2) {
        const float* W = wo + c0;
        const float* X = og + base * 128;
        const int kbeg = wave * 64;
        for (int kk = kbeg; kk < kbeg + 64; kk += 4) {
            float4 x40 = *(const float4*)(X + r0 * 128 + kk);
            float4 x41 = *(const float4*)(X + r1 * 128 + kk);
            #pragma unroll
            for (int q = 0; q < 4; q++) {
                const float4 wlo = *(const float4*)(W + (kk + q) * 128);
                const float4 whi = *(const float4*)(W + (kk + q) * 128 + 4);
                const float xa = ((const float*)&x40)[q];
                const float xb = ((const float*)&x41)[q];
                acc0[0] += xa * wlo.x; acc0[1] += xa * wlo.y;
                acc0[2] += xa * wlo.z; acc0[3] += xa * wlo.w;
                acc0[4] += xa * whi.x; acc0[5] += xa * whi.y;
                acc0[6] += xa * whi.z; acc0[7] += xa * whi.w;
                acc1[0] += xb * wlo.x; acc1[1] += xb * wlo.y;
                acc1[2] += xb * wlo.z; acc1[3] += xb * wlo.w;
                acc1[4] += xb * whi.x; acc1[5] += xb * whi.y;
                acc1[6] += xb * whi.z; acc1[7] += xb * whi.w;
            }
        }
    } else {
        const float* W = wout + c0;
        const float* X = bm + base * 256;
        const int kbeg = (wave - 2) * 128;
        for (int kk = kbeg; kk < kbeg + 128; kk += 4) {
            float4 x40 = *(const float4*)(X + r0 * 256 + kk);
            float4 x41 = *(const float4*)(X + r1 * 256 + kk);
            #pragma unroll
            for (int q = 0; q < 4; q++) {
                const float4 wlo = *(const float4*)(W + (kk + q) * 128);
                const float4 whi = *(const float4*)(W + (kk + q) * 128 + 4);
                const float xa = ((const float*)&x40)[q];
                const float xb = ((const float*)&x41)[q];
                acc0[0] += xa * wlo.x; acc0[1] += xa * wlo.y;
                acc0[2] += xa * wlo.z; acc0[3] += xa * wlo.w;
                acc0[4] += xa * whi.x; acc0[5] += xa * whi.y;
                acc0[6] += xa * whi.z; acc0[7] += xa * whi.w;
                acc1[0] += xb * wlo.x; acc1[1] += xb * wlo.y;
                acc1[2] += xb * wlo.z; acc1[3] += xb * wlo.w;
                acc1[4] += xb * whi.x; acc1[5] += xb * whi.y;
                acc1[6] += xb * whi.z; acc1[7] += xb * whi.w;
            }
        }
    }
    float* sc = scr + wave * 1056;
    *(float4*)(sc + r0 * 132 + c0)     = make_float4(acc0[0], acc0[1], acc0[2], acc0[3]);
    *(float4*)(sc + r0 * 132 + c0 + 4) = make_float4(acc0[4], acc0[5], acc0[6], acc0[7]);
    *(float4*)(sc + r1 * 132 + c0)     = make_float4(acc1[0], acc1[1], acc1[2], acc1[3]);
    *(float4*)(sc + r1 * 132 + c0 + 4) = make_float4(acc1[4], acc1[5], acc1[6], acc1[7]);
    __syncthreads();

    #pragma unroll
    for (int i2 = 0; i2 < 4; i2++) {
        const int e = t + i2 * 256;       // 1024 = 8 rows x 128 cols
        const int r = e >> 7, cc = e & 127;
        const float* s = scr + r * 132 + cc;
        const int idx = (base + r) * 128 + cc;
        out[idx] = asig[idx] * (s[0] + s[1056]) + tsig[idx] * (s[2112] + s[3168]);
    }
}

// ---------------------------------------------------------------------------
extern "C" void kernel_launch(void* const* d_in, const int* in_sizes, int n_in,
                              void* d_out, int out_size, void* d_ws, size_t ws_size,
                              hipStream_t stream)
{
    const float* q        = (const float*)d_in[0];
    const float* c        = (const float*)d_in[1];
    const float* p        = (const float*)d_in[2];
    const float* a_sg_all = (const float*)d_in[3];
    const float* a_gw_all = (const float*)d_in[4];
    const float* a_sw_all = (const float*)d_in[5];
    const float* wq_all   = (const float*)d_in[6];
    const float* bq_all   = (const float*)d_in[7];
    const float* wk_all   = (const float*)d_in[8];
    const float* wv_all   = (const float*)d_in[9];
    const float* lnzg_all = (const float*)d_in[10];
    const float* lnzb_all = (const float*)d_in[11];
    const float* wb_all   = (const float*)d_in[12];
    const float* wgt_all  = (const float*)d_in[13];
    const float* wo_all   = (const float*)d_in[14];
    const float* awso_all = (const float*)d_in[15];
    const float* abso_all = (const float*)d_in[16];
    const float* t_sg_all = (const float*)d_in[17];
    const float* t_gw_all = (const float*)d_in[18];
    const float* t_sw_all = (const float*)d_in[19];
    const float* w1_all   = (const float*)d_in[20];
    const float* w2_all   = (const float*)d_in[21];
    const float* wout_all = (const float*)d_in[22];
    const float* twso_all = (const float*)d_in[23];
    const float* tbso_all = (const float*)d_in[24];

    float* ws = (float*)d_ws;
    const size_t RC = (size_t)R_ * CQ_;   // 524288
    float* qh   = ws;
    float* kh   = ws + RC;
    float* vh   = ws + 2 * RC;
    float* gh   = ws + 3 * RC;
    float* bmb  = ws + 4 * RC;            // R*256 = 2*RC
    float* asig = ws + 6 * RC;
    float* tsig = ws + 7 * RC;
    float* abuf = ws + 8 * RC;
    float* ogb  = ws + 9 * RC;
    float* zbb  = ws + 10 * RC;           // NB*R*H*KW = 12*RC

    k_zbias<<<dim3(B_ * N_ * KW_ / 256), dim3(256), 0, stream>>>(
        p, lnzg_all, lnzb_all, wb_all, zbb);

    const float* acur = q;
    for (int blk = 0; blk < NB_; blk++) {
        k_pre<<<dim3(R_ / 8), dim3(512), 0, stream>>>(
            acur, c,
            a_sg_all + blk * CKV_, a_gw_all + blk * CKV_ * CQ_,
            a_sw_all + blk * CKV_ * CQ_, awso_all + blk * CKV_ * CQ_,
            abso_all + blk * CQ_,
            t_sg_all + blk * CKV_, t_gw_all + blk * CKV_ * CQ_,
            t_sw_all + blk * CKV_ * CQ_, twso_all + blk * CKV_ * CQ_,
            tbso_all + blk * CQ_,
            wq_all + blk * CQ_ * CQ_, bq_all + blk * CQ_,
            wk_all + blk * CQ_ * CQ_, wv_all + blk * CQ_ * CQ_,
            wgt_all + blk * CQ_ * CQ_,
            w1_all + blk * CQ_ * 2 * CQ_, w2_all + blk * CQ_ * 2 * CQ_,
            qh, kh, vh, gh, bmb, asig, tsig);
        k_attn<<<dim3(N_ / 32, H_, B_), dim3(256), 0, stream>>>(
            qh, kh, vh, gh, zbb + (size_t)blk * R_ * H_ * KW_, ogb);
        float* outp = (blk == NB_ - 1) ? (float*)d_out : abuf;
        k_combine<<<dim3(R_ / 8), dim3(256), 0, stream>>>(
            ogb, bmb, wo_all + blk * CQ_ * CQ_, wout_all + blk * 2 * CQ_ * CQ_,
            asig, tsig, outp);
        acur = abuf;
    }
}